// Round 4
// baseline (410.090 us; speedup 1.0000x reference)
//
#include <hip/hip_runtime.h>

#define NQ 8
#define DIM 256
#define NLAYER 256

typedef float v2f __attribute__((ext_vector_type(2)));

// ---------------- Kernel 1: dense per-(m,layer,qubit) gate construction ----
// U = Rz @ Ry @ Rx = [[alpha, beta], [-conj(beta), conj(alpha)]]
// g[((m*256 + i)*8 + q)] = {alpha_r, alpha_i, beta_r, beta_i}
__global__ __launch_bounds__(256) void gates_gen(
    const float* __restrict__ x,   // [M, 256]
    const float* __restrict__ p,   // [256, 8, 3]
    float4* __restrict__ g,
    int total)
{
    const int idx = blockIdx.x * 256 + threadIdx.x;
    if (idx >= total) return;
    const int q = idx & 7;
    const int i = (idx >> 3) & 255;
    const int m = idx >> 11;

    const float he = 0.5f * x[(m << 8) | i];
    const float* __restrict__ pl = p + (i * 8 + q) * 3;
    const float hx = he * pl[0];
    const float hy = he * pl[1];
    const float hz = he * pl[2];
    const float cx = __cosf(hx), sx = __sinf(hx);
    const float cy = __cosf(hy), sy = __sinf(hy);
    const float cz = __cosf(hz), sz = __sinf(hz);
    const float A = cy * cx, B = sy * sx, C = sy * cx, D = cy * sx;
    const float alr = cz * A + sz * B;
    const float ali = cz * B - sz * A;
    const float ber = -(cz * C + sz * D);
    const float bei = sz * C - cz * D;
    g[idx] = make_float4(alr, ali, ber, bei);
}

// ---------------- Kernel 2: state evolution, TWO waves per circuit ---------
// Block = 128 threads = 2 waves = 1 circuit. Amplitude y = (w<<7)|(L<<1)|s,
// s in {0,1} packed in v2f. Qubit 0 (bit 7 = wave bit) -> LDS exchange
// (double-buffered by layer parity, one barrier per layer). Qubits 1..6 ->
// lane bits 5..0 via shfl_xor. Qubit 7 -> slot bit, local. CNOT chain ==
// Gray gather: new(w,L,s) = old(w, (L^(L>>1))^(w<<5), s^(L&1)).
__global__ __launch_bounds__(128) void qemb_apply2(
    const float4* __restrict__ g,  // [M, 256, 8]
    float* __restrict__ out)       // [M, 256] real parts
{
    __shared__ float4 xbuf[2][2][64];
    const int tid = threadIdx.x;
    const int w = tid >> 6;
    const int L = tid & 63;
    const int m = blockIdx.x;

    v2f ar = {0.f, 0.f}, ai = {0.f, 0.f};
    if (tid == 0) ar.x = 1.f;   // |0...0>

    const float4* __restrict__ gm = g + ((size_t)m << 11);

    const float s0 = w ? -1.f : 1.f;
    float sgn[7];
#pragma unroll
    for (int q = 1; q < 7; ++q) sgn[q] = ((L >> (6 - q)) & 1) ? -1.f : 1.f;
    const int srcLane = (L ^ (L >> 1)) ^ (w << 5);
    const bool L0 = L & 1;

#pragma unroll 2
    for (int i = 0; i < NLAYER; ++i) {
        float4 G[8];
#pragma unroll
        for (int q = 0; q < 8; ++q) G[q] = gm[i * 8 + q];

        // q = 0 (bit 7 = wave bit): LDS exchange with partner wave
        xbuf[i & 1][w][L] = make_float4(ar.x, ai.x, ar.y, ai.y);
        __syncthreads();
        const float4 pv = xbuf[i & 1][w ^ 1][L];
        {
            const float csr = G[0].x, csi = s0 * G[0].y;
            const float cpr = s0 * G[0].z, cpi = G[0].w;
            const v2f pr = {pv.x, pv.z}, pi = {pv.y, pv.w};
            const v2f nar = csr * ar - csi * ai + cpr * pr - cpi * pi;
            const v2f nai = csr * ai + csi * ar + cpr * pi + cpi * pr;
            ar = nar; ai = nai;
        }
        // q = 1..6: cross-lane (y bit 6..1 = lane bit 5..0)
#pragma unroll
        for (int q = 1; q < 7; ++q) {
            const int mask = 64 >> q;
            v2f pr, pi;
            pr.x = __shfl_xor(ar.x, mask, 64); pr.y = __shfl_xor(ar.y, mask, 64);
            pi.x = __shfl_xor(ai.x, mask, 64); pi.y = __shfl_xor(ai.y, mask, 64);
            const float s = sgn[q];
            const float csr = G[q].x, csi = s * G[q].y;
            const float cpr = s * G[q].z, cpi = G[q].w;
            const v2f nar = csr * ar - csi * ai + cpr * pr - cpi * pi;
            const v2f nai = csr * ai + csi * ar + cpr * pi + cpi * pr;
            ar = nar; ai = nai;
        }
        // q = 7: slot-local pair
        {
            const float alr = G[7].x, ali = G[7].y, ber = G[7].z, bei = G[7].w;
            const float xr = ar.x, xi = ai.x, yr = ar.y, yi = ai.y;
            ar.x = alr * xr - ali * xi + ber * yr - bei * yi;
            ai.x = alr * xi + ali * xr + ber * yi + bei * yr;
            ar.y = -ber * xr - bei * xi + alr * yr + ali * yi;
            ai.y = -ber * xi + bei * xr + alr * yi - ali * yr;
        }
        // CNOT chain: Gray gather (source wave == own wave)
        const float t0r = __shfl(ar.x, srcLane, 64);
        const float t1r = __shfl(ar.y, srcLane, 64);
        const float t0i = __shfl(ai.x, srcLane, 64);
        const float t1i = __shfl(ai.y, srcLane, 64);
        ar.x = L0 ? t1r : t0r;  ar.y = L0 ? t0r : t1r;
        ai.x = L0 ? t1i : t0i;  ai.y = L0 ? t0i : t1i;
    }

    float2* o = reinterpret_cast<float2*>(out + ((size_t)m << 8) + (w << 7) + (L << 1));
    *o = make_float2(ar.x, ar.y);
}

// ---------------- Fallback: monolithic (known-good round-2 kernel) ---------
__global__ __launch_bounds__(256) void qemb_mono(
    const float* __restrict__ x, const float* __restrict__ p,
    float* __restrict__ out, int M)
{
    const int lane = threadIdx.x & 63;
    const int wave = threadIdx.x >> 6;
    const int m = blockIdx.x * 4 + wave;
    if (m >= M) return;
    float ar[4], ai[4];
#pragma unroll
    for (int j = 0; j < 4; ++j) { ar[j] = 0.f; ai[j] = 0.f; }
    if (lane == 0) ar[0] = 1.f;
    const float* __restrict__ xrow = x + (size_t)m * DIM;
    for (int i = 0; i < NLAYER; ++i) {
        const float he = 0.5f * xrow[i];
        const float* __restrict__ pl = p + i * (NQ * 3);
#pragma unroll
        for (int q = 0; q < NQ; ++q) {
            const float hx = he * pl[q * 3 + 0], hy = he * pl[q * 3 + 1], hz = he * pl[q * 3 + 2];
            const float cx = __cosf(hx), sx = __sinf(hx);
            const float cy = __cosf(hy), sy = __sinf(hy);
            const float cz = __cosf(hz), sz = __sinf(hz);
            const float A = cy * cx, B = sy * sx, C = sy * cx, D = cy * sx;
            const float alr = cz * A + sz * B, ali = cz * B - sz * A;
            const float ber = -(cz * C + sz * D), bei = sz * C - cz * D;
            if (q < 6) {
                const int sh = 5 - q;
                const float s = ((lane >> sh) & 1) ? -1.f : 1.f;
                const float csr = alr, csi = s * ali, cpr = s * ber, cpi = bei;
#pragma unroll
                for (int j = 0; j < 4; ++j) {
                    const float pr = __shfl_xor(ar[j], 1 << sh, 64);
                    const float pi = __shfl_xor(ai[j], 1 << sh, 64);
                    const float xr = ar[j], xi = ai[j];
                    ar[j] = csr * xr - csi * xi + cpr * pr - cpi * pi;
                    ai[j] = csr * xi + csi * xr + cpr * pi + cpi * pr;
                }
            } else {
                const int d = (q == 6) ? 2 : 1;
#pragma unroll
                for (int j0 = 0; j0 < 2; ++j0) {
                    const int a = (q == 6) ? j0 : j0 * 2, b = a + d;
                    const float xr = ar[a], xi = ai[a], yr = ar[b], yi = ai[b];
                    ar[a] = alr * xr - ali * xi + ber * yr - bei * yi;
                    ai[a] = alr * xi + ali * xr + ber * yi + bei * yr;
                    ar[b] = -ber * xr - bei * xi + alr * yr + ali * yi;
                    ai[b] = -ber * xi + bei * xr + alr * yi - ali * yr;
                }
            }
        }
        const int srcL = lane ^ (lane >> 1);
        float tr[4], ti[4];
#pragma unroll
        for (int s2 = 0; s2 < 4; ++s2) { tr[s2] = __shfl(ar[s2], srcL, 64); ti[s2] = __shfl(ai[s2], srcL, 64); }
        const int L0 = lane & 1;
        ar[0] = L0 ? tr[2] : tr[0];  ai[0] = L0 ? ti[2] : ti[0];
        ar[1] = L0 ? tr[3] : tr[1];  ai[1] = L0 ? ti[3] : ti[1];
        ar[2] = L0 ? tr[1] : tr[3];  ai[2] = L0 ? ti[1] : ti[3];
        ar[3] = L0 ? tr[0] : tr[2];  ai[3] = L0 ? ti[0] : ti[2];
    }
    float4* o = reinterpret_cast<float4*>(out + (size_t)m * DIM + lane * 4);
    *o = make_float4(ar[0], ar[1], ar[2], ar[3]);
}

extern "C" void kernel_launch(void* const* d_in, const int* in_sizes, int n_in,
                              void* d_out, int out_size, void* d_ws, size_t ws_size,
                              hipStream_t stream) {
    const float* x = (const float*)d_in[0];        // [8,256,256] fp32
    const float* qp = (const float*)d_in[1];       // [256,8,3] fp32
    float* out = (float*)d_out;                    // [8,256,256] fp32 real parts

    const int M = in_sizes[0] / DIM;               // 2048 circuits
    const size_t gates_bytes = (size_t)M * NLAYER * NQ * sizeof(float4);  // 67 MB

    if (ws_size >= gates_bytes) {
        float4* g = (float4*)d_ws;
        const int total = M * NLAYER * NQ;
        gates_gen<<<(total + 255) / 256, 256, 0, stream>>>(x, qp, g, total);
        qemb_apply2<<<M, 128, 0, stream>>>(g, out);
    } else {
        qemb_mono<<<(M + 3) / 4, 256, 0, stream>>>(x, qp, out, M);
    }
}